// Round 10
// baseline (251.183 us; speedup 1.0000x reference)
//
#include <hip/hip_runtime.h>
#include <hip/hip_bf16.h>
#include <math.h>

// Problem: SurMoE. B=32, N1=512, N2=256, D=256, H=8, HD=32, S=768.
// Outputs: gene (32,512,256) f32 then img (32,256,256) f32, concat flat.
#define B_ 32
#define N1_ 512
#define N2_ 256
#define D_ 256
#define S_ 768
#define IMG_OFF 4194304  // 32*512*256
#define QSCALE_ (0.17677669529663689f * 1.4426950408889634f)  // 1/sqrt(32) * log2(e)

typedef __attribute__((ext_vector_type(8))) short bf16x8;
typedef __attribute__((ext_vector_type(4))) float f32x4;
#define MFMA16(a, b, c) __builtin_amdgcn_mfma_f32_16x16x32_bf16(a, b, c, 0, 0, 0)

__device__ __forceinline__ ushort f2b(float f) {
  __hip_bfloat16 h = __float2bfloat16(f);
  return __builtin_bit_cast(ushort, h);
}
__device__ __forceinline__ uint pk2(float a, float b) {
  return (uint)f2b(a) | ((uint)f2b(b) << 16);
}
__device__ __forceinline__ float b2f(ushort u) {
  return __builtin_bit_cast(float, ((uint)u) << 16);
}
__device__ __forceinline__ float eluf(float v) { return v > 0.f ? v : expm1f(v); }

// async global->LDS, 16B per lane. g: per-lane global addr; l: WAVE-UNIFORM LDS base.
// HW scatters lane i to l + i*16 (m104/m108) -> unpadded tiles; we XOR-swizzle the
// SOURCE chunk per lane so reads can de-swizzle into conflict-free bank patterns.
__device__ __forceinline__ void gl16(const ushort* g, ushort* l) {
  __builtin_amdgcn_global_load_lds(
      (const __attribute__((address_space(1))) uint*)g,
      (__attribute__((address_space(3))) uint*)l, 16, 0, 0);
}

// ---------------- prep: z->bf16 staging + partial means + x2T (blocks 0..255) ----------------
// ---------------- + weights->bf16, Wq prescaled              (blocks 256..767) ----------------
// wb layout (elems): lf[0,64K) af2[64K,128K) af3[128K,256K) attn_in[256K,448K) attn_out[448K,512K)
__global__ __launch_bounds__(256) void k_prep(const float* __restrict__ x1,
                                              const float* __restrict__ x2,
                                              const float* __restrict__ lf_w,
                                              const float* __restrict__ af2_w,
                                              const float* __restrict__ af3_w,
                                              const float* __restrict__ attn_in_w,
                                              const float* __restrict__ attn_out_w,
                                              ushort* __restrict__ zb,
                                              ushort* __restrict__ wb,
                                              ushort* __restrict__ x2t,
                                              float* __restrict__ mp) {
  int t = threadIdx.x;
  if (blockIdx.x >= 256) {   // ---- weight conversion path ----
    int g = (blockIdx.x - 256)*256 + t;
    int e0 = g*4;
    const float* src; int loc; float sc = 1.f;
    if (e0 < 65536)       { src = lf_w;       loc = e0; }
    else if (e0 < 131072) { src = af2_w;      loc = e0 - 65536; }
    else if (e0 < 262144) { src = af3_w;      loc = e0 - 131072; }
    else if (e0 < 458752) { src = attn_in_w;  loc = e0 - 262144; if (loc < 65536) sc = QSCALE_; }
    else                  { src = attn_out_w; loc = e0 - 458752; }
    float4 v = *(const float4*)(src + loc);
    *(ushort4*)(wb + e0) = make_ushort4(f2b(v.x*sc), f2b(v.y*sc), f2b(v.z*sc), f2b(v.w*sc));
    return;
  }
  int b = blockIdx.x >> 3, s = blockIdx.x & 7;
  int c = t & 63;    // float4-column
  int rg = t >> 6;   // 0..3
  __shared__ float red[4][260];
  __shared__ ushort xt[32][266];
  float4 s1 = {0.f, 0.f, 0.f, 0.f};
  for (int i = 0; i < 16; ++i) {
    int r = s*64 + rg*16 + i;
    float4 v = *(const float4*)(x1 + ((size_t)(b*N1_) + r)*D_ + c*4);
    s1.x += v.x; s1.y += v.y; s1.z += v.z; s1.w += v.w;
    uint2 pk; pk.x = pk2(v.x, v.y); pk.y = pk2(v.z, v.w);
    *(uint2*)(zb + (size_t)b*196608 + (size_t)r*256 + c*4) = pk;
  }
  red[rg][c*4+0] = s1.x; red[rg][c*4+1] = s1.y; red[rg][c*4+2] = s1.z; red[rg][c*4+3] = s1.w;
  __syncthreads();
  {
    float v = red[0][t] + red[1][t] + red[2][t] + red[3][t];
    mp[(size_t)(b*8+s)*512 + t] = v * (1.0f/512.0f);
  }
  __syncthreads();
  float4 s2 = {0.f, 0.f, 0.f, 0.f};
  for (int i = 0; i < 8; ++i) {
    int rl = rg*8 + i;
    int r = s*32 + rl;
    float4 v = *(const float4*)(x2 + ((size_t)(b*N2_) + r)*D_ + c*4);
    s2.x += v.x; s2.y += v.y; s2.z += v.z; s2.w += v.w;
    ushort b0 = f2b(v.x), b1 = f2b(v.y), b2 = f2b(v.z), b3 = f2b(v.w);
    uint2 pk; pk.x = (uint)b0 | ((uint)b1 << 16); pk.y = (uint)b2 | ((uint)b3 << 16);
    *(uint2*)(zb + (size_t)b*196608 + (size_t)(512 + r)*256 + c*4) = pk;
    xt[rl][c*4+0] = b0; xt[rl][c*4+1] = b1; xt[rl][c*4+2] = b2; xt[rl][c*4+3] = b3;
  }
  red[rg][c*4+0] = s2.x; red[rg][c*4+1] = s2.y; red[rg][c*4+2] = s2.z; red[rg][c*4+3] = s2.w;
  __syncthreads();
  {
    float v = red[0][t] + red[1][t] + red[2][t] + red[3][t];
    mp[(size_t)(b*8+s)*512 + 256 + t] = v * (1.0f/256.0f);
  }
  // x2T: thread t owns d=t, writes n2 = s*32..s*32+31 (32 ushorts = 4 uint4)
  ushort* dst = x2t + (size_t)b*65536 + (size_t)t*256 + s*32;
  #pragma unroll
  for (int g = 0; g < 4; ++g) {
    uint4 w;
    w.x = (uint)xt[g*8+0][t] | ((uint)xt[g*8+1][t] << 16);
    w.y = (uint)xt[g*8+2][t] | ((uint)xt[g*8+3][t] << 16);
    w.z = (uint)xt[g*8+4][t] | ((uint)xt[g*8+5][t] << 16);
    w.w = (uint)xt[g*8+6][t] | ((uint)xt[g*8+7][t] << 16);
    *(uint4*)(dst + g*8) = w;
  }
}

// ---------------- router head ----------------
__global__ __launch_bounds__(256) void k_head(const float* __restrict__ mp, const float* __restrict__ r_w1,
                       const float* __restrict__ r_b1, const float* __restrict__ ln_g,
                       const float* __restrict__ ln_b, const float* __restrict__ r_w2,
                       const float* __restrict__ r_b2, float* __restrict__ wout) {
  int b = blockIdx.x;
  int j = threadIdx.x;  // 256
  __shared__ __align__(16) float ms[512];
  __shared__ float red[256];
  float a0 = 0.f, a1 = 0.f;
  for (int s = 0; s < 8; ++s) {
    a0 += mp[(size_t)(b*8+s)*512 + j];
    a1 += mp[(size_t)(b*8+s)*512 + 256 + j];
  }
  ms[j] = a0; ms[j+256] = a1;
  __syncthreads();
  float4 accv = {0.f, 0.f, 0.f, 0.f};
  const float4* wrow4 = (const float4*)(r_w1 + (size_t)j*512);
  const float4* ms4 = (const float4*)ms;
  for (int k = 0; k < 128; ++k) {
    float4 w = wrow4[k], m = ms4[k];
    accv.x += w.x*m.x; accv.y += w.y*m.y; accv.z += w.z*m.z; accv.w += w.w*m.w;
  }
  float acc = r_b1[j] + (accv.x + accv.y) + (accv.z + accv.w);
  red[j] = acc; __syncthreads();
  for (int off=128; off>0; off>>=1){ if (j<off) red[j]+=red[j+off]; __syncthreads(); }
  float mu = red[0] * (1.f/256.f); __syncthreads();
  float cd = acc - mu;
  red[j] = cd*cd; __syncthreads();
  for (int off=128; off>0; off>>=1){ if (j<off) red[j]+=red[j+off]; __syncthreads(); }
  float var = red[0]*(1.f/256.f); __syncthreads();
  float xn = cd * rsqrtf(var + 1e-5f) * ln_g[j] + ln_b[j];
  float h = 0.5f*xn*(1.f+erff(xn*0.70710678118654752f));
  float lg[4];
  for (int e=0;e<4;++e){
    red[j] = h * r_w2[e*256 + j]; __syncthreads();
    for (int off=128; off>0; off>>=1){ if (j<off) red[j]+=red[j+off]; __syncthreads(); }
    lg[e] = red[0] + r_b2[e]; __syncthreads();
  }
  if (j==0){
    float mx = fmaxf(fmaxf(lg[0],lg[1]),fmaxf(lg[2],lg[3]));
    float e0=expf(lg[0]-mx),e1=expf(lg[1]-mx),e2=expf(lg[2]-mx),e3=expf(lg[3]-mx);
    float s=e0+e1+e2+e3;
    wout[b*4+0]=e0/s; wout[b*4+1]=e1/s; wout[b*4+2]=e2/s; wout[b*4+3]=e3/s;
  }
}

// ---------------- qkv (128x128 tiles, async + XOR swizzle): q->qo, k->kh, v->vT ----------------
__global__ __launch_bounds__(256) void k_qkv(const ushort* __restrict__ zb, const ushort* __restrict__ wb,
                      const float* __restrict__ bias,
                      ushort* __restrict__ qo, ushort* __restrict__ kh,
                      ushort* __restrict__ vt) {
  int ct = blockIdx.x, nt = blockIdx.y, b = blockIdx.z;
  int tid = threadIdx.x;
  int lane = tid & 63, wid = tid >> 6;
  int wm = wid >> 1, wn = wid & 1;
  int l15 = lane & 15, quad = lane >> 4;
  __shared__ __align__(16) ushort As[128][64];
  __shared__ __align__(16) ushort Ws[128][64];
  f32x4 acc[4][4] = {};
  int n0 = nt*128, c0 = ct*128;
  // staging: row = wid*32 + j*8 + rl8, LDS chunk cp holds global chunk cp^rl8
  int rl8 = lane >> 3, ss = (lane & 7) ^ rl8;
  const ushort* g_a = zb + (size_t)b*196608 + (size_t)(n0 + wid*32 + rl8)*256 + ss*8;
  const ushort* g_w = wb + 262144 + (size_t)(c0 + wid*32 + rl8)*256 + ss*8;
  int l7 = l15 & 7;
  for (int k0 = 0; k0 < 256; k0 += 64) {
    #pragma unroll
    for (int j = 0; j < 4; ++j) {
      gl16(g_a + (size_t)j*8*256 + k0, &As[wid*32 + j*8][0]);
      gl16(g_w + (size_t)j*8*256 + k0, &Ws[wid*32 + j*8][0]);
    }
    __syncthreads();
    #pragma unroll
    for (int kc = 0; kc < 2; ++kc) {
      int cpx = ((kc*4 + quad) ^ l7) * 8;   // de-swizzled chunk
      bf16x8 af[4], bfr[4];
      #pragma unroll
      for (int im = 0; im < 4; ++im) af[im] = *(bf16x8*)&As[wm*64 + im*16 + l15][cpx];
      #pragma unroll
      for (int in = 0; in < 4; ++in) bfr[in] = *(bf16x8*)&Ws[wn*64 + in*16 + l15][cpx];
      #pragma unroll
      for (int im = 0; im < 4; ++im)
        #pragma unroll
        for (int in = 0; in < 4; ++in)
          acc[im][in] = MFMA16(af[im], bfr[in], acc[im][in]);
    }
    __syncthreads();
  }
  if (ct < 2) {          // q: prescaled, [b][n][256]
    #pragma unroll
    for (int im = 0; im < 4; ++im)
      #pragma unroll
      for (int reg = 0; reg < 4; ++reg) {
        int n = n0 + wm*64 + im*16 + quad*4 + reg;
        #pragma unroll
        for (int in = 0; in < 4; ++in) {
          int c = c0 + wn*64 + in*16 + l15;
          qo[((size_t)(b*S_)+n)*256 + c] = f2b(acc[im][in][reg] + bias[c]*QSCALE_);
        }
      }
  } else if (ct < 4) {   // k: kh[b][h][n][32]
    #pragma unroll
    for (int im = 0; im < 4; ++im)
      #pragma unroll
      for (int reg = 0; reg < 4; ++reg) {
        int n = n0 + wm*64 + im*16 + quad*4 + reg;
        #pragma unroll
        for (int in = 0; in < 4; ++in) {
          int c = c0 + wn*64 + in*16 + l15;        // global col in [256,512)
          int kc2 = c - 256; int h = kc2 >> 5, d = kc2 & 31;
          kh[(((size_t)(b*8+h))*S_ + n)*32 + d] = f2b(acc[im][in][reg] + bias[c]);
        }
      }
  } else {               // v: vT[b][h][32][768]
    #pragma unroll
    for (int im = 0; im < 4; ++im) {
      int nb = n0 + wm*64 + im*16 + quad*4;
      #pragma unroll
      for (int in = 0; in < 4; ++in) {
        int c = c0 + wn*64 + in*16 + l15;          // [512,768)
        float bs = bias[c];
        int vcol = c - 512; int h = vcol >> 5, d = vcol & 31;
        uint2 pk;
        pk.x = pk2(acc[im][in][0] + bs, acc[im][in][1] + bs);
        pk.y = pk2(acc[im][in][2] + bs, acc[im][in][3] + bs);
        *(uint2*)&vt[(((size_t)(b*8+h))*32 + d)*S_ + nb] = pk;
      }
    }
  }
}

// ---------------- flash attention, no-max softmax, 192 q/block, async + swizzled staging ----
// grid (h=8, b=32, qhf=4): blocks sharing (b,h) differ by 256 in linear id (=0 mod 8 -> same XCD).
// o aliases qo: block reads exactly the q-slice it overwrites.
__global__ __launch_bounds__(256) void k_attn(const ushort* __restrict__ qo,
                                              const ushort* __restrict__ kh,
                                              const ushort* __restrict__ vt,
                                              ushort* __restrict__ obuf) {
  int h = blockIdx.x, b = blockIdx.y, qhf = blockIdx.z;
  int tid = threadIdx.x;
  int lane = tid & 63, w = tid >> 6;
  int l15 = lane & 15, quad = lane >> 4;
  __shared__ __align__(16) ushort Ks2[32][64];   // row-paired K: row'=n>>1, chunks: (n&1)*4 + kchunk
  __shared__ __align__(16) ushort Vts[32][64];
  __shared__ __align__(16) ushort Ps[4][16][72];

  int qbase = qhf*192 + w*48;
  bf16x8 bq[3];
  #pragma unroll
  for (int u = 0; u < 3; ++u)
    bq[u] = *(const bf16x8*)(qo + ((size_t)(b*S_) + qbase + u*16 + l15)*256 + h*32 + quad*8);

  f32x4 ao[3][2] = {};
  float lacc[3] = {};

  const ushort* khb = kh + ((size_t)(b*8+h))*S_*32;
  const ushort* vtb = vt + ((size_t)(b*8+h))*32*S_;
  // staging lanes: row = w*8 + rl8, LDS chunk cp holds global srcsel cp^rl8
  int rl8 = lane >> 3, ss = (lane & 7) ^ rl8;
  // Ks2: srcsel -> n = 2*row' + (ss>>2), kchunk = ss&3
  const ushort* g_k = khb + (size_t)(2*(w*8 + rl8) + (ss >> 2))*32 + (ss & 3)*8;
  // Vts: srcsel -> n-chunk ss along the row (stride S)
  const ushort* g_v = vtb + (size_t)(w*8 + rl8)*S_ + ss*8;

  int cpk = (((l15 & 1)*4 + quad) ^ ((l15 >> 1) & 7)) * 8;  // K de-swizzle
  int l7 = l15 & 7;

  for (int kt = 0; kt < 12; ++kt) {
    __syncthreads();
    gl16(g_k + (size_t)kt*64*32, &Ks2[w*8][0]);
    gl16(g_v + kt*64, &Vts[w*8][0]);
    __syncthreads();

    bf16x8 ak[4];
    #pragma unroll
    for (int t = 0; t < 4; ++t) ak[t] = *(bf16x8*)&Ks2[t*8 + (l15 >> 1)][cpk];
    bf16x8 av[2][2];
    #pragma unroll
    for (int im = 0; im < 2; ++im)
      #pragma unroll
      for (int kc = 0; kc < 2; ++kc)
        av[im][kc] = *(bf16x8*)&Vts[im*16 + l15][((kc*4 + quad) ^ l7) * 8];

    #pragma unroll
    for (int u = 0; u < 3; ++u) {
      f32x4 sf[4];
      #pragma unroll
      for (int t = 0; t < 4; ++t) {
        f32x4 z = {0.f, 0.f, 0.f, 0.f};
        sf[t] = MFMA16(ak[t], bq[u], z);   // S^T·log2e (scale folded into q)
      }
      #pragma unroll
      for (int t = 0; t < 4; ++t) {
        float p0 = __builtin_amdgcn_exp2f(sf[t][0]);
        float p1 = __builtin_amdgcn_exp2f(sf[t][1]);
        float p2 = __builtin_amdgcn_exp2f(sf[t][2]);
        float p3 = __builtin_amdgcn_exp2f(sf[t][3]);
        lacc[u] += (p0 + p1) + (p2 + p3);
        uint2 pk;
        pk.x = pk2(p0, p1);
        pk.y = pk2(p2, p3);
        *(uint2*)&Ps[w][l15][t*16 + quad*4] = pk;
      }
      #pragma unroll
      for (int kc = 0; kc < 2; ++kc) {
        bf16x8 bp = *(bf16x8*)&Ps[w][l15][kc*32 + quad*8];
        ao[u][0] = MFMA16(av[0][kc], bp, ao[u][0]);
        ao[u][1] = MFMA16(av[1][kc], bp, ao[u][1]);
      }
    }
  }
  #pragma unroll
  for (int u = 0; u < 3; ++u) {
    float l = lacc[u];
    l += __shfl_xor(l, 16, 64);
    l += __shfl_xor(l, 32, 64);
    float linv = 1.f / l;
    int n = qbase + u*16 + l15;
    ushort* orow = obuf + ((size_t)(b*S_)+n)*256 + h*32;
    #pragma unroll
    for (int im = 0; im < 2; ++im) {
      uint2 pk;
      pk.x = pk2(ao[u][im][0]*linv, ao[u][im][1]*linv);
      pk.y = pk2(ao[u][im][2]*linv, ao[u][im][3]*linv);
      *(uint2*)(orow + im*16 + quad*4) = pk;
    }
  }
}

// ---------------- fused output: out = w0*elu(lf) + w1*(elu(a1)+elu(a2)) + w2*proj + w3*z ----------------
// Single fused k-loop, K=32 chunks, async staging into PAIR-FUSED [64][64] tiles with
// XOR chunk swizzle -> conflict-free b128 reads. 32KB LDS -> 5 blocks/CU.
__global__ __launch_bounds__(256) void k_out(const ushort* __restrict__ zb, const ushort* __restrict__ wb,
                      const ushort* __restrict__ ob, const ushort* __restrict__ x2t,
                      const float* __restrict__ lf_b, const float* __restrict__ af2_b,
                      const float* __restrict__ af3_b, const float* __restrict__ ao_b,
                      const float* __restrict__ wgt, float* __restrict__ out) {
  int dt = blockIdx.x, nt = blockIdx.y, b = blockIdx.z;
  int tid = threadIdx.x;
  int lane = tid & 63, wid = tid >> 6;
  int wm = wid >> 1, wn = wid & 1;
  int l15 = lane & 15, quad = lane >> 4;
  __shared__ __align__(16) ushort PAB[64][64];  // A1 (z rows)    | A2 (x1 rows)
  __shared__ __align__(16) ushort PCD[64][64];  // A3 (af3 rows)  | A4 (o rows)
  __shared__ __align__(16) ushort PWX[64][64];  // W1 (lf_w)      | W2 (af2_w)
  __shared__ __align__(16) ushort PYZ[64][64];  // W3 (x2^T)      | W4 (attn_out_w)
  f32x4 a_lf[2][2] = {}, a_a1[2][2] = {}, a_a2[2][2] = {}, a_pj[2][2] = {};
  int n0 = nt*64, d0 = dt*64;
  int xr0 = ((nt < 8) ? nt : (nt - 8)) * 64;   // xout row base (x1/af3 rows)

  // staging: row = wid*16 + j*8 + rl8; LDS chunk cp holds srcsel = cp ^ rl8;
  // srcsel<4 -> first member chunk srcsel; else second member chunk srcsel-4.
  int rl8 = lane >> 3, ss = (lane & 7) ^ rl8;
  int sel2 = ss >> 2;            // 0: first member, 1: second
  int km = (ss & 3) * 8;         // k-chunk offset within member
  int r_st = wid*16 + rl8;
  const ushort* pAB = (sel2 ? zb + (size_t)b*196608 + (size_t)(xr0+r_st)*256
                            : zb + (size_t)b*196608 + (size_t)(n0+r_st)*256) + km;
  const ushort* pCD = (sel2 ? ob + ((size_t)(b*S_) + n0 + r_st)*256
                            : wb + 131072 + (size_t)(xr0+r_st)*256) + km;
  const ushort* pWX = (sel2 ? wb + 65536 + (size_t)(d0+r_st)*256
                            : wb + (size_t)(d0+r_st)*256) + km;
  const ushort* pYZ = (sel2 ? wb + 458752 + (size_t)(d0+r_st)*256
                            : x2t + (size_t)b*65536 + (size_t)(d0+r_st)*256) + km;

  int l7 = l15 & 7;
  int c1 = (quad ^ l7) * 8;          // de-swizzle, first member
  int c2 = ((quad + 4) ^ l7) * 8;    // second member

  for (int k0 = 0; k0 < 256; k0 += 32) {
    #pragma unroll
    for (int j = 0; j < 2; ++j) {
      gl16(pAB + k0 + j*2048, &PAB[wid*16 + j*8][0]);
      gl16(pCD + k0 + j*2048, &PCD[wid*16 + j*8][0]);
      gl16(pWX + k0 + j*2048, &PWX[wid*16 + j*8][0]);
      gl16(pYZ + k0 + j*2048, &PYZ[wid*16 + j*8][0]);
    }
    __syncthreads();
    {
      bf16x8 x0, x1r, y0, y1;
      x0 = *(bf16x8*)&PAB[wm*32 + l15][c1];  x1r = *(bf16x8*)&PAB[wm*32 + 16 + l15][c1];
      y0 = *(bf16x8*)&PWX[wn*32 + l15][c1];  y1  = *(bf16x8*)&PWX[wn*32 + 16 + l15][c1];
      a_lf[0][0] = MFMA16(x0, y0, a_lf[0][0]);  a_lf[0][1] = MFMA16(x0, y1, a_lf[0][1]);
      a_lf[1][0] = MFMA16(x1r, y0, a_lf[1][0]); a_lf[1][1] = MFMA16(x1r, y1, a_lf[1][1]);
      x0 = *(bf16x8*)&PAB[wm*32 + l15][c2];  x1r = *(bf16x8*)&PAB[wm*32 + 16 + l15][c2];
      y0 = *(bf16x8*)&PWX[wn*32 + l15][c2];  y1  = *(bf16x8*)&PWX[wn*32 + 16 + l15][c2];
      a_a1[0][0] = MFMA16(x0, y0, a_a1[0][0]);  a_a1[0][1] = MFMA16(x0, y1, a_a1[0][1]);
      a_a1[1][0] = MFMA16(x1r, y0, a_a1[1][0]); a_a1[1][1] = MFMA16(x1r, y1, a_a1[1][1]);
      x0 = *(bf16x8*)&PCD[wm*32 + l15][c1];  x1r = *(bf16x8*)&PCD[wm*32 + 16 + l15][c1];
      y0 = *(bf16x8*)&PYZ[wn*32 + l15][c1];  y1  = *(bf16x8*)&PYZ[wn*32 + 16 + l15][c1];
      a_a2[0][0] = MFMA16(x0, y0, a_a2[0][0]);  a_a2[0][1] = MFMA16(x0, y1, a_a2[0][1]);
      a_a2[1][0] = MFMA16(x1r, y0, a_a2[1][0]); a_a2[1][1] = MFMA16(x1r, y1, a_a2[1][1]);
      x0 = *(bf16x8*)&PCD[wm*32 + l15][c2];  x1r = *(bf16x8*)&PCD[wm*32 + 16 + l15][c2];
      y0 = *(bf16x8*)&PYZ[wn*32 + l15][c2];  y1  = *(bf16x8*)&PYZ[wn*32 + 16 + l15][c2];
      a_pj[0][0] = MFMA16(x0, y0, a_pj[0][0]);  a_pj[0][1] = MFMA16(x0, y1, a_pj[0][1]);
      a_pj[1][0] = MFMA16(x1r, y0, a_pj[1][0]); a_pj[1][1] = MFMA16(x1r, y1, a_pj[1][1]);
    }
    __syncthreads();
  }
  // ---- epilogue (z-term from bf16 zb; rows L2-hot from staging) ----
  float w0 = wgt[b*4+0], w1v = wgt[b*4+1], w2v = wgt[b*4+2], w3 = wgt[b*4+3];
  #pragma unroll
  for (int im = 0; im < 2; ++im) {
    #pragma unroll
    for (int reg = 0; reg < 4; ++reg) {
      int rl = wm*32 + im*16 + quad*4 + reg;   // local row
      int n = n0 + rl;
      int rx = xr0 + rl;                        // xout row (x1/af3 index)
      const ushort* zr = zb + (size_t)b*196608 + (size_t)n*256;
      float* orw = (nt < 8) ? out + ((size_t)(b*N1_) + n)*D_
                            : out + (size_t)IMG_OFF + ((size_t)(b*N2_) + (n - 512))*D_;
      float b3 = af3_b[rx];
      #pragma unroll
      for (int in = 0; in < 2; ++in) {
        int d = d0 + wn*32 + in*16 + l15;
        float v = w0*eluf(a_lf[im][in][reg] + lf_b[d])
                + w1v*(eluf(a_a1[im][in][reg] + af2_b[d]) + eluf(a_a2[im][in][reg] + b3))
                + w2v*(a_pj[im][in][reg] + ao_b[d])
                + w3*b2f(zr[d]);
        orw[d] = v;
      }
    }
  }
}

extern "C" void kernel_launch(void* const* d_in, const int* in_sizes, int n_in,
                              void* d_out, int out_size, void* d_ws, size_t ws_size,
                              hipStream_t stream) {
  const float* x1        = (const float*)d_in[0];
  const float* x2        = (const float*)d_in[1];
  const float* r_w1      = (const float*)d_in[2];
  const float* r_b1      = (const float*)d_in[3];
  const float* ln_g      = (const float*)d_in[4];
  const float* ln_b      = (const float*)d_in[5];
  const float* r_w2      = (const float*)d_in[6];
  const float* r_b2      = (const float*)d_in[7];
  const float* lf_b      = (const float*)d_in[9];
  const float* af2_b     = (const float*)d_in[11];
  const float* af3_b     = (const float*)d_in[13];
  const float* attn_in_b = (const float*)d_in[15];
  const float* attn_out_b= (const float*)d_in[17];
  float* out = (float*)d_out;

  // ws: mp[131072 f32] | w[128 f32] | zb | qo(=o) | kh | vt (each B*S*256 ush)
  //     | wb[524288 ush] | x2t[B*256*256 ush]  ~= 56.4 MB
  float* ws_mp = (float*)d_ws;
  float* ws_w  = ws_mp + 131072;
  ushort* ws_zb = (ushort*)(ws_w + 128);
  ushort* ws_qo = ws_zb + (size_t)B_*S_*256;
  ushort* ws_kh = ws_qo + (size_t)B_*S_*256;
  ushort* ws_vt = ws_kh + (size_t)B_*S_*256;
  ushort* ws_wb = ws_vt + (size_t)B_*S_*256;
  ushort* ws_xt = ws_wb + 524288;

  k_prep<<<dim3(768), 256, 0, stream>>>(x1, x2, (const float*)d_in[8], (const float*)d_in[10],
                                        (const float*)d_in[12], (const float*)d_in[14],
                                        (const float*)d_in[16], ws_zb, ws_wb, ws_xt, ws_mp);
  k_head<<<dim3(B_),   256, 0, stream>>>(ws_mp, r_w1, r_b1, ln_g, ln_b, r_w2, r_b2, ws_w);
  k_qkv <<<dim3(6,6,B_), 256, 0, stream>>>(ws_zb, ws_wb, attn_in_b, ws_qo, ws_kh, ws_vt);
  k_attn<<<dim3(8,B_,4), 256, 0, stream>>>(ws_qo, ws_kh, ws_vt, ws_qo);
  k_out <<<dim3(4,12,B_),256, 0, stream>>>(ws_zb, ws_wb, ws_qo, ws_xt,
                                           lf_b, af2_b, af3_b, attn_out_b, ws_w, out);
}

// Round 11
// 242.161 us; speedup vs baseline: 1.0373x; 1.0373x over previous
//
#include <hip/hip_runtime.h>
#include <hip/hip_bf16.h>
#include <math.h>

// Problem: SurMoE. B=32, N1=512, N2=256, D=256, H=8, HD=32, S=768.
// Outputs: gene (32,512,256) f32 then img (32,256,256) f32, concat flat.
#define B_ 32
#define N1_ 512
#define N2_ 256
#define D_ 256
#define S_ 768
#define IMG_OFF 4194304  // 32*512*256
#define QSCALE_ (0.17677669529663689f * 1.4426950408889634f)  // 1/sqrt(32) * log2(e)

typedef __attribute__((ext_vector_type(8))) short bf16x8;
typedef __attribute__((ext_vector_type(4))) float f32x4;
#define MFMA16(a, b, c) __builtin_amdgcn_mfma_f32_16x16x32_bf16(a, b, c, 0, 0, 0)

__device__ __forceinline__ ushort f2b(float f) {
  __hip_bfloat16 h = __float2bfloat16(f);
  return __builtin_bit_cast(ushort, h);
}
__device__ __forceinline__ uint pk2(float a, float b) {
  return (uint)f2b(a) | ((uint)f2b(b) << 16);
}
__device__ __forceinline__ float b2f(ushort u) {
  return __builtin_bit_cast(float, ((uint)u) << 16);
}
__device__ __forceinline__ float eluf(float v) { return v > 0.f ? v : expm1f(v); }

// async global->LDS, 16B per lane. g: per-lane global addr; l: WAVE-UNIFORM LDS base.
// HW scatters lane i to l + i*16 (m104/m108). Keep ONE array + monotonic segments
// per instruction (R10 lesson); XOR-swizzle only the chunk WITHIN a row.
__device__ __forceinline__ void gl16(const ushort* g, ushort* l) {
  __builtin_amdgcn_global_load_lds(
      (const __attribute__((address_space(1))) uint*)g,
      (__attribute__((address_space(3))) uint*)l, 16, 0, 0);
}

// ---------------- prep: z->bf16 staging + partial means + x2T (blocks 0..255) ----------------
// ---------------- + weights->bf16, Wq prescaled              (blocks 256..767) ----------------
// wb layout (elems): lf[0,64K) af2[64K,128K) af3[128K,256K) attn_in[256K,448K) attn_out[448K,512K)
__global__ __launch_bounds__(256) void k_prep(const float* __restrict__ x1,
                                              const float* __restrict__ x2,
                                              const float* __restrict__ lf_w,
                                              const float* __restrict__ af2_w,
                                              const float* __restrict__ af3_w,
                                              const float* __restrict__ attn_in_w,
                                              const float* __restrict__ attn_out_w,
                                              ushort* __restrict__ zb,
                                              ushort* __restrict__ wb,
                                              ushort* __restrict__ x2t,
                                              float* __restrict__ mp) {
  int t = threadIdx.x;
  if (blockIdx.x >= 256) {   // ---- weight conversion path ----
    int g = (blockIdx.x - 256)*256 + t;
    int e0 = g*4;
    const float* src; int loc; float sc = 1.f;
    if (e0 < 65536)       { src = lf_w;       loc = e0; }
    else if (e0 < 131072) { src = af2_w;      loc = e0 - 65536; }
    else if (e0 < 262144) { src = af3_w;      loc = e0 - 131072; }
    else if (e0 < 458752) { src = attn_in_w;  loc = e0 - 262144; if (loc < 65536) sc = QSCALE_; }
    else                  { src = attn_out_w; loc = e0 - 458752; }
    float4 v = *(const float4*)(src + loc);
    *(ushort4*)(wb + e0) = make_ushort4(f2b(v.x*sc), f2b(v.y*sc), f2b(v.z*sc), f2b(v.w*sc));
    return;
  }
  int b = blockIdx.x >> 3, s = blockIdx.x & 7;
  int c = t & 63;    // float4-column
  int rg = t >> 6;   // 0..3
  __shared__ float red[4][260];
  __shared__ ushort xt[32][266];
  float4 s1 = {0.f, 0.f, 0.f, 0.f};
  for (int i = 0; i < 16; ++i) {
    int r = s*64 + rg*16 + i;
    float4 v = *(const float4*)(x1 + ((size_t)(b*N1_) + r)*D_ + c*4);
    s1.x += v.x; s1.y += v.y; s1.z += v.z; s1.w += v.w;
    uint2 pk; pk.x = pk2(v.x, v.y); pk.y = pk2(v.z, v.w);
    *(uint2*)(zb + (size_t)b*196608 + (size_t)r*256 + c*4) = pk;
  }
  red[rg][c*4+0] = s1.x; red[rg][c*4+1] = s1.y; red[rg][c*4+2] = s1.z; red[rg][c*4+3] = s1.w;
  __syncthreads();
  {
    float v = red[0][t] + red[1][t] + red[2][t] + red[3][t];
    mp[(size_t)(b*8+s)*512 + t] = v * (1.0f/512.0f);
  }
  __syncthreads();
  float4 s2 = {0.f, 0.f, 0.f, 0.f};
  for (int i = 0; i < 8; ++i) {
    int rl = rg*8 + i;
    int r = s*32 + rl;
    float4 v = *(const float4*)(x2 + ((size_t)(b*N2_) + r)*D_ + c*4);
    s2.x += v.x; s2.y += v.y; s2.z += v.z; s2.w += v.w;
    ushort b0 = f2b(v.x), b1 = f2b(v.y), b2 = f2b(v.z), b3 = f2b(v.w);
    uint2 pk; pk.x = (uint)b0 | ((uint)b1 << 16); pk.y = (uint)b2 | ((uint)b3 << 16);
    *(uint2*)(zb + (size_t)b*196608 + (size_t)(512 + r)*256 + c*4) = pk;
    xt[rl][c*4+0] = b0; xt[rl][c*4+1] = b1; xt[rl][c*4+2] = b2; xt[rl][c*4+3] = b3;
  }
  red[rg][c*4+0] = s2.x; red[rg][c*4+1] = s2.y; red[rg][c*4+2] = s2.z; red[rg][c*4+3] = s2.w;
  __syncthreads();
  {
    float v = red[0][t] + red[1][t] + red[2][t] + red[3][t];
    mp[(size_t)(b*8+s)*512 + 256 + t] = v * (1.0f/256.0f);
  }
  // x2T: thread t owns d=t, writes n2 = s*32..s*32+31 (32 ushorts = 4 uint4)
  ushort* dst = x2t + (size_t)b*65536 + (size_t)t*256 + s*32;
  #pragma unroll
  for (int g = 0; g < 4; ++g) {
    uint4 w;
    w.x = (uint)xt[g*8+0][t] | ((uint)xt[g*8+1][t] << 16);
    w.y = (uint)xt[g*8+2][t] | ((uint)xt[g*8+3][t] << 16);
    w.z = (uint)xt[g*8+4][t] | ((uint)xt[g*8+5][t] << 16);
    w.w = (uint)xt[g*8+6][t] | ((uint)xt[g*8+7][t] << 16);
    *(uint4*)(dst + g*8) = w;
  }
}

// ---------------- router head ----------------
__global__ __launch_bounds__(256) void k_head(const float* __restrict__ mp, const float* __restrict__ r_w1,
                       const float* __restrict__ r_b1, const float* __restrict__ ln_g,
                       const float* __restrict__ ln_b, const float* __restrict__ r_w2,
                       const float* __restrict__ r_b2, float* __restrict__ wout) {
  int b = blockIdx.x;
  int j = threadIdx.x;  // 256
  __shared__ __align__(16) float ms[512];
  __shared__ float red[256];
  float a0 = 0.f, a1 = 0.f;
  for (int s = 0; s < 8; ++s) {
    a0 += mp[(size_t)(b*8+s)*512 + j];
    a1 += mp[(size_t)(b*8+s)*512 + 256 + j];
  }
  ms[j] = a0; ms[j+256] = a1;
  __syncthreads();
  float4 accv = {0.f, 0.f, 0.f, 0.f};
  const float4* wrow4 = (const float4*)(r_w1 + (size_t)j*512);
  const float4* ms4 = (const float4*)ms;
  for (int k = 0; k < 128; ++k) {
    float4 w = wrow4[k], m = ms4[k];
    accv.x += w.x*m.x; accv.y += w.y*m.y; accv.z += w.z*m.z; accv.w += w.w*m.w;
  }
  float acc = r_b1[j] + (accv.x + accv.y) + (accv.z + accv.w);
  red[j] = acc; __syncthreads();
  for (int off=128; off>0; off>>=1){ if (j<off) red[j]+=red[j+off]; __syncthreads(); }
  float mu = red[0] * (1.f/256.f); __syncthreads();
  float cd = acc - mu;
  red[j] = cd*cd; __syncthreads();
  for (int off=128; off>0; off>>=1){ if (j<off) red[j]+=red[j+off]; __syncthreads(); }
  float var = red[0]*(1.f/256.f); __syncthreads();
  float xn = cd * rsqrtf(var + 1e-5f) * ln_g[j] + ln_b[j];
  float h = 0.5f*xn*(1.f+erff(xn*0.70710678118654752f));
  float lg[4];
  for (int e=0;e<4;++e){
    red[j] = h * r_w2[e*256 + j]; __syncthreads();
    for (int off=128; off>0; off>>=1){ if (j<off) red[j]+=red[j+off]; __syncthreads(); }
    lg[e] = red[0] + r_b2[e]; __syncthreads();
  }
  if (j==0){
    float mx = fmaxf(fmaxf(lg[0],lg[1]),fmaxf(lg[2],lg[3]));
    float e0=expf(lg[0]-mx),e1=expf(lg[1]-mx),e2=expf(lg[2]-mx),e3=expf(lg[3]-mx);
    float s=e0+e1+e2+e3;
    wout[b*4+0]=e0/s; wout[b*4+1]=e1/s; wout[b*4+2]=e2/s; wout[b*4+3]=e3/s;
  }
}

// ---------------- qkv (128x128 tiles, async + XOR swizzle): q->qo, k->kh, v->vT ----------------
__global__ __launch_bounds__(256) void k_qkv(const ushort* __restrict__ zb, const ushort* __restrict__ wb,
                      const float* __restrict__ bias,
                      ushort* __restrict__ qo, ushort* __restrict__ kh,
                      ushort* __restrict__ vt) {
  int ct = blockIdx.x, nt = blockIdx.y, b = blockIdx.z;
  int tid = threadIdx.x;
  int lane = tid & 63, wid = tid >> 6;
  int wm = wid >> 1, wn = wid & 1;
  int l15 = lane & 15, quad = lane >> 4;
  __shared__ __align__(16) ushort As[128][64];
  __shared__ __align__(16) ushort Ws[128][64];
  f32x4 acc[4][4] = {};
  int n0 = nt*128, c0 = ct*128;
  // staging: row = wid*32 + j*8 + rl8, LDS chunk cp holds global chunk cp^rl8
  int rl8 = lane >> 3, ss = (lane & 7) ^ rl8;
  const ushort* g_a = zb + (size_t)b*196608 + (size_t)(n0 + wid*32 + rl8)*256 + ss*8;
  const ushort* g_w = wb + 262144 + (size_t)(c0 + wid*32 + rl8)*256 + ss*8;
  int l7 = l15 & 7;
  for (int k0 = 0; k0 < 256; k0 += 64) {
    #pragma unroll
    for (int j = 0; j < 4; ++j) {
      gl16(g_a + (size_t)j*8*256 + k0, &As[wid*32 + j*8][0]);
      gl16(g_w + (size_t)j*8*256 + k0, &Ws[wid*32 + j*8][0]);
    }
    __syncthreads();
    #pragma unroll
    for (int kc = 0; kc < 2; ++kc) {
      int cpx = ((kc*4 + quad) ^ l7) * 8;   // de-swizzled chunk
      bf16x8 af[4], bfr[4];
      #pragma unroll
      for (int im = 0; im < 4; ++im) af[im] = *(bf16x8*)&As[wm*64 + im*16 + l15][cpx];
      #pragma unroll
      for (int in = 0; in < 4; ++in) bfr[in] = *(bf16x8*)&Ws[wn*64 + in*16 + l15][cpx];
      #pragma unroll
      for (int im = 0; im < 4; ++im)
        #pragma unroll
        for (int in = 0; in < 4; ++in)
          acc[im][in] = MFMA16(af[im], bfr[in], acc[im][in]);
    }
    __syncthreads();
  }
  if (ct < 2) {          // q: prescaled, [b][n][256]
    #pragma unroll
    for (int im = 0; im < 4; ++im)
      #pragma unroll
      for (int reg = 0; reg < 4; ++reg) {
        int n = n0 + wm*64 + im*16 + quad*4 + reg;
        #pragma unroll
        for (int in = 0; in < 4; ++in) {
          int c = c0 + wn*64 + in*16 + l15;
          qo[((size_t)(b*S_)+n)*256 + c] = f2b(acc[im][in][reg] + bias[c]*QSCALE_);
        }
      }
  } else if (ct < 4) {   // k: kh[b][h][n][32]
    #pragma unroll
    for (int im = 0; im < 4; ++im)
      #pragma unroll
      for (int reg = 0; reg < 4; ++reg) {
        int n = n0 + wm*64 + im*16 + quad*4 + reg;
        #pragma unroll
        for (int in = 0; in < 4; ++in) {
          int c = c0 + wn*64 + in*16 + l15;        // global col in [256,512)
          int kc2 = c - 256; int h = kc2 >> 5, d = kc2 & 31;
          kh[(((size_t)(b*8+h))*S_ + n)*32 + d] = f2b(acc[im][in][reg] + bias[c]);
        }
      }
  } else {               // v: vT[b][h][32][768]
    #pragma unroll
    for (int im = 0; im < 4; ++im) {
      int nb = n0 + wm*64 + im*16 + quad*4;
      #pragma unroll
      for (int in = 0; in < 4; ++in) {
        int c = c0 + wn*64 + in*16 + l15;          // [512,768)
        float bs = bias[c];
        int vcol = c - 512; int h = vcol >> 5, d = vcol & 31;
        uint2 pk;
        pk.x = pk2(acc[im][in][0] + bs, acc[im][in][1] + bs);
        pk.y = pk2(acc[im][in][2] + bs, acc[im][in][3] + bs);
        *(uint2*)&vt[(((size_t)(b*8+h))*32 + d)*S_ + nb] = pk;
      }
    }
  }
}

// ---------------- flash attention, no-max softmax, 192 q/block, async + swizzled staging ----
// grid (h=8, b=32, qhf=4): blocks sharing (b,h) differ by 256 in linear id (=0 mod 8 -> same XCD).
// o aliases qo: block reads exactly the q-slice it overwrites.
__global__ __launch_bounds__(256) void k_attn(const ushort* __restrict__ qo,
                                              const ushort* __restrict__ kh,
                                              const ushort* __restrict__ vt,
                                              ushort* __restrict__ obuf) {
  int h = blockIdx.x, b = blockIdx.y, qhf = blockIdx.z;
  int tid = threadIdx.x;
  int lane = tid & 63, w = tid >> 6;
  int l15 = lane & 15, quad = lane >> 4;
  __shared__ __align__(16) ushort Ks2[32][64];   // row-paired K: row'=n>>1, chunks: (n&1)*4 + kchunk
  __shared__ __align__(16) ushort Vts[32][64];
  __shared__ __align__(16) ushort Ps[4][16][72];

  int qbase = qhf*192 + w*48;
  bf16x8 bq[3];
  #pragma unroll
  for (int u = 0; u < 3; ++u)
    bq[u] = *(const bf16x8*)(qo + ((size_t)(b*S_) + qbase + u*16 + l15)*256 + h*32 + quad*8);

  f32x4 ao[3][2] = {};
  float lacc[3] = {};

  const ushort* khb = kh + ((size_t)(b*8+h))*S_*32;
  const ushort* vtb = vt + ((size_t)(b*8+h))*32*S_;
  // staging lanes: row = w*8 + rl8, LDS chunk cp holds global srcsel cp^rl8
  int rl8 = lane >> 3, ss = (lane & 7) ^ rl8;
  // Ks2: srcsel -> n = 2*row' + (ss>>2), kchunk = ss&3
  const ushort* g_k = khb + (size_t)(2*(w*8 + rl8) + (ss >> 2))*32 + (ss & 3)*8;
  // Vts: srcsel -> n-chunk ss along the row (stride S)
  const ushort* g_v = vtb + (size_t)(w*8 + rl8)*S_ + ss*8;

  int cpk = (((l15 & 1)*4 + quad) ^ ((l15 >> 1) & 7)) * 8;  // K de-swizzle
  int l7 = l15 & 7;

  for (int kt = 0; kt < 12; ++kt) {
    __syncthreads();
    gl16(g_k + (size_t)kt*64*32, &Ks2[w*8][0]);
    gl16(g_v + kt*64, &Vts[w*8][0]);
    __syncthreads();

    bf16x8 ak[4];
    #pragma unroll
    for (int t = 0; t < 4; ++t) ak[t] = *(bf16x8*)&Ks2[t*8 + (l15 >> 1)][cpk];
    bf16x8 av[2][2];
    #pragma unroll
    for (int im = 0; im < 2; ++im)
      #pragma unroll
      for (int kc = 0; kc < 2; ++kc)
        av[im][kc] = *(bf16x8*)&Vts[im*16 + l15][((kc*4 + quad) ^ l7) * 8];

    #pragma unroll
    for (int u = 0; u < 3; ++u) {
      f32x4 sf[4];
      #pragma unroll
      for (int t = 0; t < 4; ++t) {
        f32x4 z = {0.f, 0.f, 0.f, 0.f};
        sf[t] = MFMA16(ak[t], bq[u], z);   // S^T·log2e (scale folded into q)
      }
      #pragma unroll
      for (int t = 0; t < 4; ++t) {
        float p0 = __builtin_amdgcn_exp2f(sf[t][0]);
        float p1 = __builtin_amdgcn_exp2f(sf[t][1]);
        float p2 = __builtin_amdgcn_exp2f(sf[t][2]);
        float p3 = __builtin_amdgcn_exp2f(sf[t][3]);
        lacc[u] += (p0 + p1) + (p2 + p3);
        uint2 pk;
        pk.x = pk2(p0, p1);
        pk.y = pk2(p2, p3);
        *(uint2*)&Ps[w][l15][t*16 + quad*4] = pk;
      }
      #pragma unroll
      for (int kc = 0; kc < 2; ++kc) {
        bf16x8 bp = *(bf16x8*)&Ps[w][l15][kc*32 + quad*8];
        ao[u][0] = MFMA16(av[0][kc], bp, ao[u][0]);
        ao[u][1] = MFMA16(av[1][kc], bp, ao[u][1]);
      }
    }
  }
  #pragma unroll
  for (int u = 0; u < 3; ++u) {
    float l = lacc[u];
    l += __shfl_xor(l, 16, 64);
    l += __shfl_xor(l, 32, 64);
    float linv = 1.f / l;
    int n = qbase + u*16 + l15;
    ushort* orow = obuf + ((size_t)(b*S_)+n)*256 + h*32;
    #pragma unroll
    for (int im = 0; im < 2; ++im) {
      uint2 pk;
      pk.x = pk2(ao[u][im][0]*linv, ao[u][im][1]*linv);
      pk.y = pk2(ao[u][im][2]*linv, ao[u][im][3]*linv);
      *(uint2*)(orow + im*16 + quad*4) = pk;
    }
  }
}

// ---------------- fused output: out = w0*elu(lf) + w1*(elu(a1)+elu(a2)) + w2*proj + w3*z ----------------
// Single fused k-loop, K=32 chunks, async staging: ONE array per gl16 (monotonic 16x64B
// segments) + intra-row 4-chunk XOR swizzle -> conflict-free b128 reads. 32KB LDS.
__global__ __launch_bounds__(256) void k_out(const ushort* __restrict__ zb, const ushort* __restrict__ wb,
                      const ushort* __restrict__ ob, const ushort* __restrict__ x2t,
                      const float* __restrict__ lf_b, const float* __restrict__ af2_b,
                      const float* __restrict__ af3_b, const float* __restrict__ ao_b,
                      const float* __restrict__ wgt, float* __restrict__ out) {
  int dt = blockIdx.x, nt = blockIdx.y, b = blockIdx.z;
  int tid = threadIdx.x;
  int lane = tid & 63, wid = tid >> 6;
  int wm = wid >> 1, wn = wid & 1;
  int l15 = lane & 15, quad = lane >> 4;
  __shared__ __align__(16) ushort A1[64][32];
  __shared__ __align__(16) ushort A2[64][32];
  __shared__ __align__(16) ushort A3[64][32];
  __shared__ __align__(16) ushort A4[64][32];
  __shared__ __align__(16) ushort W1s[64][32];
  __shared__ __align__(16) ushort W2s[64][32];
  __shared__ __align__(16) ushort W3s[64][32];
  __shared__ __align__(16) ushort W4s[64][32];
  f32x4 a_lf[2][2] = {}, a_a1[2][2] = {}, a_a2[2][2] = {}, a_pj[2][2] = {};
  int n0 = nt*64, d0 = dt*64;
  int xr0 = ((nt < 8) ? nt : (nt - 8)) * 64;   // xout row base (x1/af3 rows)
  // staging: row r = wid*16 + (lane>>2); LDS chunk cp=lane&3 holds global chunk
  // cp ^ ((r>>1)&3) = cp ^ ((lane>>3)&3)  -> reads de-swizzle with quad^((l15>>1)&3)
  int sr = tid >> 2;
  int sc4 = (((lane & 3) ^ ((lane >> 3) & 3))) * 8;

  const ushort* p_a1 = zb + (size_t)b*196608 + (size_t)(n0+sr)*256 + sc4;   // z rows
  const ushort* p_a2 = zb + (size_t)b*196608 + (size_t)(xr0+sr)*256 + sc4;  // x1 rows
  const ushort* p_a3 = wb + 131072 + (size_t)(xr0+sr)*256 + sc4;            // af3 rows
  const ushort* p_a4 = ob + ((size_t)(b*S_) + n0 + sr)*256 + sc4;           // o rows
  const ushort* p_w1 = wb + (size_t)(d0+sr)*256 + sc4;                      // lf_w
  const ushort* p_w2 = wb + 65536 + (size_t)(d0+sr)*256 + sc4;              // af2_w
  const ushort* p_w3 = x2t + (size_t)b*65536 + (size_t)(d0+sr)*256 + sc4;   // x2^T rows (d)
  const ushort* p_w4 = wb + 458752 + (size_t)(d0+sr)*256 + sc4;             // attn_out_w
  ushort* l_a1 = &A1[wid*16][0];
  ushort* l_a2 = &A2[wid*16][0];
  ushort* l_a3 = &A3[wid*16][0];
  ushort* l_a4 = &A4[wid*16][0];
  ushort* l_w1 = &W1s[wid*16][0];
  ushort* l_w2 = &W2s[wid*16][0];
  ushort* l_w3 = &W3s[wid*16][0];
  ushort* l_w4 = &W4s[wid*16][0];

  int cq = (quad ^ ((l15 >> 1) & 3)) * 8;   // de-swizzled read chunk (same for all rows used)

  for (int k0 = 0; k0 < 256; k0 += 32) {
    gl16(p_a1 + k0, l_a1);
    gl16(p_a2 + k0, l_a2);
    gl16(p_a3 + k0, l_a3);
    gl16(p_a4 + k0, l_a4);
    gl16(p_w1 + k0, l_w1);
    gl16(p_w2 + k0, l_w2);
    gl16(p_w3 + k0, l_w3);
    gl16(p_w4 + k0, l_w4);
    __syncthreads();
    {
      bf16x8 x0, x1r, y0, y1;
      x0 = *(bf16x8*)&A1[wm*32 + l15][cq];  x1r = *(bf16x8*)&A1[wm*32 + 16 + l15][cq];
      y0 = *(bf16x8*)&W1s[wn*32 + l15][cq]; y1  = *(bf16x8*)&W1s[wn*32 + 16 + l15][cq];
      a_lf[0][0] = MFMA16(x0, y0, a_lf[0][0]);  a_lf[0][1] = MFMA16(x0, y1, a_lf[0][1]);
      a_lf[1][0] = MFMA16(x1r, y0, a_lf[1][0]); a_lf[1][1] = MFMA16(x1r, y1, a_lf[1][1]);
      x0 = *(bf16x8*)&A2[wm*32 + l15][cq];  x1r = *(bf16x8*)&A2[wm*32 + 16 + l15][cq];
      y0 = *(bf16x8*)&W2s[wn*32 + l15][cq]; y1  = *(bf16x8*)&W2s[wn*32 + 16 + l15][cq];
      a_a1[0][0] = MFMA16(x0, y0, a_a1[0][0]);  a_a1[0][1] = MFMA16(x0, y1, a_a1[0][1]);
      a_a1[1][0] = MFMA16(x1r, y0, a_a1[1][0]); a_a1[1][1] = MFMA16(x1r, y1, a_a1[1][1]);
      x0 = *(bf16x8*)&A3[wm*32 + l15][cq];  x1r = *(bf16x8*)&A3[wm*32 + 16 + l15][cq];
      y0 = *(bf16x8*)&W3s[wn*32 + l15][cq]; y1  = *(bf16x8*)&W3s[wn*32 + 16 + l15][cq];
      a_a2[0][0] = MFMA16(x0, y0, a_a2[0][0]);  a_a2[0][1] = MFMA16(x0, y1, a_a2[0][1]);
      a_a2[1][0] = MFMA16(x1r, y0, a_a2[1][0]); a_a2[1][1] = MFMA16(x1r, y1, a_a2[1][1]);
      x0 = *(bf16x8*)&A4[wm*32 + l15][cq];  x1r = *(bf16x8*)&A4[wm*32 + 16 + l15][cq];
      y0 = *(bf16x8*)&W4s[wn*32 + l15][cq]; y1  = *(bf16x8*)&W4s[wn*32 + 16 + l15][cq];
      a_pj[0][0] = MFMA16(x0, y0, a_pj[0][0]);  a_pj[0][1] = MFMA16(x0, y1, a_pj[0][1]);
      a_pj[1][0] = MFMA16(x1r, y0, a_pj[1][0]); a_pj[1][1] = MFMA16(x1r, y1, a_pj[1][1]);
    }
    __syncthreads();
  }
  // ---- epilogue (z-term from bf16 zb; rows L2-hot from staging) ----
  float w0 = wgt[b*4+0], w1v = wgt[b*4+1], w2v = wgt[b*4+2], w3 = wgt[b*4+3];
  #pragma unroll
  for (int im = 0; im < 2; ++im) {
    #pragma unroll
    for (int reg = 0; reg < 4; ++reg) {
      int rl = wm*32 + im*16 + quad*4 + reg;   // local row
      int n = n0 + rl;
      int rx = xr0 + rl;                        // xout row (x1/af3 index)
      const ushort* zr = zb + (size_t)b*196608 + (size_t)n*256;
      float* orw = (nt < 8) ? out + ((size_t)(b*N1_) + n)*D_
                            : out + (size_t)IMG_OFF + ((size_t)(b*N2_) + (n - 512))*D_;
      float b3 = af3_b[rx];
      #pragma unroll
      for (int in = 0; in < 2; ++in) {
        int d = d0 + wn*32 + in*16 + l15;
        float v = w0*eluf(a_lf[im][in][reg] + lf_b[d])
                + w1v*(eluf(a_a1[im][in][reg] + af2_b[d]) + eluf(a_a2[im][in][reg] + b3))
                + w2v*(a_pj[im][in][reg] + ao_b[d])
                + w3*b2f(zr[d]);
        orw[d] = v;
      }
    }
  }
}

extern "C" void kernel_launch(void* const* d_in, const int* in_sizes, int n_in,
                              void* d_out, int out_size, void* d_ws, size_t ws_size,
                              hipStream_t stream) {
  const float* x1        = (const float*)d_in[0];
  const float* x2        = (const float*)d_in[1];
  const float* r_w1      = (const float*)d_in[2];
  const float* r_b1      = (const float*)d_in[3];
  const float* ln_g      = (const float*)d_in[4];
  const float* ln_b      = (const float*)d_in[5];
  const float* r_w2      = (const float*)d_in[6];
  const float* r_b2      = (const float*)d_in[7];
  const float* lf_b      = (const float*)d_in[9];
  const float* af2_b     = (const float*)d_in[11];
  const float* af3_b     = (const float*)d_in[13];
  const float* attn_in_b = (const float*)d_in[15];
  const float* attn_out_b= (const float*)d_in[17];
  float* out = (float*)d_out;

  // ws: mp[131072 f32] | w[128 f32] | zb | qo(=o) | kh | vt (each B*S*256 ush)
  //     | wb[524288 ush] | x2t[B*256*256 ush]  ~= 56.4 MB
  float* ws_mp = (float*)d_ws;
  float* ws_w  = ws_mp + 131072;
  ushort* ws_zb = (ushort*)(ws_w + 128);
  ushort* ws_qo = ws_zb + (size_t)B_*S_*256;
  ushort* ws_kh = ws_qo + (size_t)B_*S_*256;
  ushort* ws_vt = ws_kh + (size_t)B_*S_*256;
  ushort* ws_wb = ws_vt + (size_t)B_*S_*256;
  ushort* ws_xt = ws_wb + 524288;

  k_prep<<<dim3(768), 256, 0, stream>>>(x1, x2, (const float*)d_in[8], (const float*)d_in[10],
                                        (const float*)d_in[12], (const float*)d_in[14],
                                        (const float*)d_in[16], ws_zb, ws_wb, ws_xt, ws_mp);
  k_head<<<dim3(B_),   256, 0, stream>>>(ws_mp, r_w1, r_b1, ln_g, ln_b, r_w2, r_b2, ws_w);
  k_qkv <<<dim3(6,6,B_), 256, 0, stream>>>(ws_zb, ws_wb, attn_in_b, ws_qo, ws_kh, ws_vt);
  k_attn<<<dim3(8,B_,4), 256, 0, stream>>>(ws_qo, ws_kh, ws_vt, ws_qo);
  k_out <<<dim3(4,12,B_),256, 0, stream>>>(ws_zb, ws_wb, ws_qo, ws_xt,
                                           lf_b, af2_b, af3_b, attn_out_b, ws_w, out);
}